// Round 7
// baseline (533.703 us; speedup 1.0000x reference)
//
#include <hip/hip_runtime.h>
#include <hip/hip_bf16.h>

#define SLOPE 0.2f
#define EPS_GN 1e-5f
#define APITCH 136  // LDS row pitch in bf16 elems (272 B): 16B-aligned, breaks power-of-2 bank aliasing
#define NBUCK 391   // ceil(100000/256) dst-buckets of 256 nodes

typedef __attribute__((ext_vector_type(8))) short bfrag;   // 8 bf16 = 4 VGPR (MFMA A/B operand)
typedef __attribute__((ext_vector_type(4))) float ffrag;   // 4 fp32 accumulator

__device__ __forceinline__ float lrelu(float v) { return v > 0.f ? v : SLOPE * v; }
__device__ __forceinline__ unsigned int flipf(float x) {
    unsigned int u = __float_as_uint(x);
    return (u & 0x80000000u) ? ~u : (u | 0x80000000u);
}
__device__ __forceinline__ float unflipf(unsigned int u) {
    return __uint_as_float((u & 0x80000000u) ? (u & 0x7fffffffu) : ~u);
}
__device__ __forceinline__ short f2bs(float v) {
    __hip_bfloat16 h = __float2bfloat16(v);
    return *reinterpret_cast<short*>(&h);
}
__device__ __forceinline__ float blo(unsigned int u) { return __uint_as_float(u << 16); }
__device__ __forceinline__ float bhi(unsigned int u) { return __uint_as_float(u & 0xffff0000u); }

// ---------------- zero scratch ----------------
__global__ void zero_kernel(float* __restrict__ p, int n) {
    int i = blockIdx.x * 256 + threadIdx.x;
    if (i < n) p[i] = 0.f;
}

// ------- weight prep: WT1b[c][k] = bf16((w1@enc_w)[c,k]), bc1 = w1@enc_b ------
__global__ void prep_weights(const float* __restrict__ enc_w,
                             const float* __restrict__ enc_b,
                             const float* __restrict__ w1,
                             const float* __restrict__ w2,
                             unsigned short* __restrict__ WT1b,
                             unsigned short* __restrict__ WT2b,
                             float* __restrict__ bc1, float* __restrict__ bc2) {
    int c = blockIdx.x;   // 128 blocks (output channel)
    int k = threadIdx.x;  // 128 threads (input channel)
    __shared__ float w1row[128];
    w1row[k] = w1[c * 128 + k];
    __syncthreads();
    float acc = 0.f;
    for (int j = 0; j < 128; ++j)
        acc = fmaf(w1row[j], enc_w[j * 128 + k], acc);
    WT1b[c * 128 + k] = (unsigned short)f2bs(acc);
    WT2b[c * 128 + k] = (unsigned short)f2bs(w2[c * 128 + k]);
    if (k == 0) {
        float b = 0.f;
        for (int j = 0; j < 128; ++j) b += w1row[j] * enc_b[j];
        bc1[c] = b;
        bc2[c] = 0.f;
    }
}

// ============ CSR build: two-level bucketed counting sort =====================
// bucket b = dst >> 8 (256 nodes/bucket). Staged word = (src<<8)|(dst&255).

__global__ void __launch_bounds__(256) bucket_hist(const int* __restrict__ ei,
                                                   int* __restrict__ bhist, int E, int N) {
    __shared__ int h[NBUCK];
    for (int i = threadIdx.x; i < NBUCK; i += 256) h[i] = 0;
    __syncthreads();
    int base = blockIdx.x * 4096;
#pragma unroll
    for (int s = 0; s < 16; ++s) {
        int e = base + s * 256 + threadIdx.x;
        if (e < E + N) {
            int dst = (e < E) ? ei[E + e] : (e - E);
            atomicAdd(&h[dst >> 8], 1);
        }
    }
    __syncthreads();
    for (int i = threadIdx.x; i < NBUCK; i += 256)
        if (h[i]) atomicAdd(&bhist[i], h[i]);
}

__global__ void bucket_scan(const int* __restrict__ bhist,
                            int* __restrict__ bbase, int* __restrict__ bcur) {
    __shared__ int sh[512];
    int t = threadIdx.x;  // 512 threads
    int v = (t < NBUCK) ? bhist[t] : 0;
    sh[t] = v;
    __syncthreads();
    for (int off = 1; off < 512; off <<= 1) {
        int add = (t >= off) ? sh[t - off] : 0;
        __syncthreads();
        sh[t] += add;
        __syncthreads();
    }
    if (t < NBUCK) {
        bbase[t] = sh[t] - v;
        bcur[t] = sh[t] - v;
    }
}

__global__ void __launch_bounds__(256) bucket_scatter(const int* __restrict__ ei,
                                                      int* __restrict__ bcur,
                                                      unsigned int* __restrict__ staging,
                                                      int E, int N) {
    __shared__ int h[NBUCK];
    __shared__ int lb[NBUCK];
    for (int i = threadIdx.x; i < NBUCK; i += 256) h[i] = 0;
    __syncthreads();
    int base = blockIdx.x * 4096;
    int srcv[16], dstv[16];
#pragma unroll
    for (int s = 0; s < 16; ++s) {
        int e = base + s * 256 + threadIdx.x;
        srcv[s] = -1;
        if (e < E + N) {
            srcv[s] = (e < E) ? ei[e] : (e - E);
            dstv[s] = (e < E) ? ei[E + e] : (e - E);
            atomicAdd(&h[dstv[s] >> 8], 1);
        }
    }
    __syncthreads();
    for (int i = threadIdx.x; i < NBUCK; i += 256) {
        int c = h[i];
        lb[i] = c ? atomicAdd(&bcur[i], c) : 0;
        h[i] = 0;  // reuse as within-block cursor
    }
    __syncthreads();
#pragma unroll
    for (int s = 0; s < 16; ++s) {
        if (srcv[s] >= 0) {
            int b = dstv[s] >> 8;
            int slot = atomicAdd(&h[b], 1);
            staging[lb[b] + slot] = ((unsigned int)srcv[s] << 8) | (unsigned int)(dstv[s] & 255);
        }
    }
}

// fused: per-bucket degree hist -> LDS exclusive scan -> rowp -> CSR scatter.
__global__ void __launch_bounds__(256) bucket_finalize(
    const unsigned int* __restrict__ staging,
    const int* __restrict__ bbase, const int* __restrict__ bcur,
    int* __restrict__ rowp, int* __restrict__ esrc, int N, int Etot) {
    int b = blockIdx.x, t = threadIdx.x;
    __shared__ int h[256], sc[256];
    h[t] = 0;
    __syncthreads();
    int s0 = bbase[b], s1 = bcur[b];
    for (int j = s0 + t; j < s1; j += 256)
        atomicAdd(&h[staging[j] & 255], 1);
    __syncthreads();
    int d = h[t];
    sc[t] = d;
    __syncthreads();
    for (int off = 1; off < 256; off <<= 1) {
        int add = (t >= off) ? sc[t - off] : 0;
        __syncthreads();
        sc[t] += add;
        __syncthreads();
    }
    int excl = s0 + sc[t] - d;
    int node = b * 256 + t;
    if (node < N) rowp[node] = excl;
    if (b == 0 && t == 0) rowp[N] = Etot;
    __syncthreads();
    h[t] = excl;  // within-bucket cursors
    __syncthreads();
    for (int j = s0 + t; j < s1; j += 256) {
        unsigned int p = staging[j];
        int pos = atomicAdd(&h[p & 255], 1);
        esrc[pos] = (int)(p >> 8);
    }
}

// --------- MFMA GEMM: H[n][128] (bf16) = act(A[n][128]) @ WT^T + bc; + scores --
__global__ void __launch_bounds__(256) gemm_mfma(
    const void* __restrict__ Ain, const unsigned short* __restrict__ WTb,
    const float* __restrict__ bias, const float* __restrict__ att_src,
    const float* __restrict__ att_dst, const int* __restrict__ batch,
    const float* __restrict__ Ac, const float* __restrict__ Bc,
    unsigned int* __restrict__ H, float* __restrict__ ssrc, float* __restrict__ sdst, int N) {
    __shared__ short Bsh[128 * APITCH];  // [c][k] bf16
    __shared__ short Ash[64 * APITCH];   // [node][k] bf16 (reused for C)
    __shared__ float asrc_s[128], adst_s[128], bias_s[128];
    int tid = threadIdx.x;
    int base = blockIdx.x * 64;

    for (int idx = tid; idx < 2048; idx += 256) {
        int c = idx >> 4, k8 = (idx & 15) * 8;
        uint4 wv = ((const uint4*)WTb)[idx];
        *(uint4*)&Bsh[c * APITCH + k8] = wv;
    }
    if (Ac == nullptr) {
        const float* A = (const float*)Ain;
        for (int idx = tid; idx < 2048; idx += 256) {
            int nl = idx >> 5, k4 = (idx & 31) * 4;
            int node = base + nl;
            float4 v = make_float4(0.f, 0.f, 0.f, 0.f);
            if (node < N) v = ((const float4*)A)[node * 32 + (idx & 31)];
            *(short4*)&Ash[nl * APITCH + k4] =
                make_short4(f2bs(v.x), f2bs(v.y), f2bs(v.z), f2bs(v.w));
        }
    } else {
        const uint4* A4 = (const uint4*)Ain;
        for (int idx = tid; idx < 1024; idx += 256) {
            int nl = idx >> 4, u4 = idx & 15, k8 = u4 * 8;
            int node = base + nl;
            short o[8] = {0, 0, 0, 0, 0, 0, 0, 0};
            if (node < N) {
                uint4 hb = A4[node * 16 + u4];
                int g = batch[node];
                float4 a0 = *(const float4*)&Ac[g * 128 + k8];
                float4 a1 = *(const float4*)&Ac[g * 128 + k8 + 4];
                float4 b0 = *(const float4*)&Bc[g * 128 + k8];
                float4 b1 = *(const float4*)&Bc[g * 128 + k8 + 4];
                o[0] = f2bs(fmaf(blo(hb.x), a0.x, b0.x));
                o[1] = f2bs(fmaf(bhi(hb.x), a0.y, b0.y));
                o[2] = f2bs(fmaf(blo(hb.y), a0.z, b0.z));
                o[3] = f2bs(fmaf(bhi(hb.y), a0.w, b0.w));
                o[4] = f2bs(fmaf(blo(hb.z), a1.x, b1.x));
                o[5] = f2bs(fmaf(bhi(hb.z), a1.y, b1.y));
                o[6] = f2bs(fmaf(blo(hb.w), a1.z, b1.z));
                o[7] = f2bs(fmaf(bhi(hb.w), a1.w, b1.w));
            }
            *(bfrag*)&Ash[nl * APITCH + k8] = *(bfrag*)o;
        }
    }
    if (tid < 128) {
        asrc_s[tid] = att_src[tid];
        adst_s[tid] = att_dst[tid];
        bias_s[tid] = bias[tid];
    }
    __syncthreads();

    int w = tid >> 6, lane = tid & 63, col = lane & 15, quad = lane >> 4;
    int rowBase = w * 16;

    bfrag afr[4];
#pragma unroll
    for (int s = 0; s < 4; ++s)
        afr[s] = *(const bfrag*)&Ash[(rowBase + col) * APITCH + s * 32 + quad * 8];

    ffrag acc[8];
#pragma unroll
    for (int t = 0; t < 8; ++t) acc[t] = (ffrag){0.f, 0.f, 0.f, 0.f};

#pragma unroll
    for (int t = 0; t < 8; ++t) {
#pragma unroll
        for (int s = 0; s < 4; ++s) {
            bfrag bfr = *(const bfrag*)&Bsh[(t * 16 + col) * APITCH + s * 32 + quad * 8];
            acc[t] = __builtin_amdgcn_mfma_f32_16x16x32_bf16(afr[s], bfr, acc[t], 0, 0, 0);
        }
    }

#pragma unroll
    for (int t = 0; t < 8; ++t) {
        int ch = t * 16 + col;
        float bv = bias_s[ch];
#pragma unroll
        for (int r = 0; r < 4; ++r)
            Ash[(rowBase + quad * 4 + r) * APITCH + ch] = f2bs(acc[t][r] + bv);
    }
    __syncthreads();

    float2 av = make_float2(asrc_s[lane * 2], asrc_s[lane * 2 + 1]);
    float2 dv = make_float2(adst_s[lane * 2], adst_s[lane * 2 + 1]);
    for (int r = 0; r < 16; ++r) {
        int node = base + rowBase + r;
        unsigned int hb = *(const unsigned int*)&Ash[(rowBase + r) * APITCH + lane * 2];
        float hx = blo(hb);
        float hy = bhi(hb);
        float vs = hx * av.x + hy * av.y;
        float vd = hx * dv.x + hy * dv.y;
#pragma unroll
        for (int off = 8; off; off >>= 1) {
            vs += __shfl_xor(vs, off, 16);
            vd += __shfl_xor(vd, off, 16);
        }
        if (node < N) {
            H[node * 64 + lane] = hb;
            if ((lane & 15) == 0) {
                int h = lane >> 4;
                ssrc[node * 4 + h] = vs;
                sdst[node * 4 + h] = vd;
            }
        }
    }
}

// ------- aggregation + fused GraphNorm stats (+ optional raw max/min pool) ----
// block = 256 thr = 4 waves; wave w handles 16 consecutive dsts; block = 64 dsts
// (<=2 groups per block since batch is sorted and groups avg ~1563 nodes).
// wave = 4 edge-slots x 16 lanes; lane owns 8 contiguous channels (one head).
template <int POOL>
__global__ void __launch_bounds__(256) agg_kernel(
    const int* __restrict__ row, const int* __restrict__ esrc,
    const float* __restrict__ ssrc, const float* __restrict__ sdst,
    const uint4* __restrict__ H4, const float* __restrict__ bias,
    uint4* __restrict__ out, const int* __restrict__ batch,
    float* __restrict__ gsum, float* __restrict__ gsq, int* __restrict__ gcnt,
    int countFlag, unsigned int* __restrict__ rawmax,
    unsigned int* __restrict__ rawmin, int N) {
    __shared__ float Ls[4][2][128], Lq[4][2][128];
    __shared__ float Lmx[4][2][128], Lmn[4][2][128];
    __shared__ int cnt2[2];
    int tid = threadIdx.x, w = tid >> 6, lane = tid & 63;
    int slot = lane >> 4, li = lane & 15, head = li >> 2;
    int base = blockIdx.x * 64;
    int g0 = batch[base];
    int g1 = batch[min(base + 63, N - 1)];
    if (tid < 2) cnt2[tid] = 0;
    int c0 = li * 8;
    float bv[8];
#pragma unroll
    for (int p = 0; p < 8; ++p) bv[p] = bias[c0 + p];

    // zero this wave's LDS slices (slot0 lanes own channels c0..c0+7 exclusively)
    if (slot == 0) {
#pragma unroll
        for (int p = 0; p < 8; ++p) {
            Ls[w][0][c0 + p] = 0.f; Ls[w][1][c0 + p] = 0.f;
            Lq[w][0][c0 + p] = 0.f; Lq[w][1][c0 + p] = 0.f;
            if (POOL) {
                Lmx[w][0][c0 + p] = -3e38f; Lmx[w][1][c0 + p] = -3e38f;
                Lmn[w][0][c0 + p] =  3e38f; Lmn[w][1][c0 + p] =  3e38f;
            }
        }
    }

    float sAcc[8] = {}, qAcc[8] = {};
    float mxA[8], mnA[8];
#pragma unroll
    for (int p = 0; p < 8; ++p) { mxA[p] = -3e38f; mnA[p] = 3e38f; }
    int curSet = 0;

    for (int j = 0; j < 16; ++j) {
        int n = base + w * 16 + j;
        if (n >= N) break;
        int beg = row[n], end = row[n + 1];
        float sdh = sdst[n * 4 + head];
        float num[8] = {0.f, 0.f, 0.f, 0.f, 0.f, 0.f, 0.f, 0.f};
        float den = 0.f;
        for (int e = beg + slot; e < end; e += 4) {
            int s = esrc[e];
            float al = __expf(lrelu(ssrc[s * 4 + head] + sdh));
            uint4 hb = H4[s * 16 + li];
            den += al;
            num[0] = fmaf(al, blo(hb.x), num[0]);
            num[1] = fmaf(al, bhi(hb.x), num[1]);
            num[2] = fmaf(al, blo(hb.y), num[2]);
            num[3] = fmaf(al, bhi(hb.y), num[3]);
            num[4] = fmaf(al, blo(hb.z), num[4]);
            num[5] = fmaf(al, bhi(hb.z), num[5]);
            num[6] = fmaf(al, blo(hb.w), num[6]);
            num[7] = fmaf(al, bhi(hb.w), num[7]);
        }
        den += __shfl_xor(den, 16);
        den += __shfl_xor(den, 32);
#pragma unroll
        for (int p = 0; p < 8; ++p) {
            num[p] += __shfl_xor(num[p], 16);
            num[p] += __shfl_xor(num[p], 32);
        }
        if (slot == 0) {
            int bset = (batch[n] != g0) ? 1 : 0;  // uniform over wave's 16 lanes
            if (bset != curSet) {
                // flush set-0 accumulators (at most one transition per wave)
#pragma unroll
                for (int p = 0; p < 8; ++p) {
                    Ls[w][curSet][c0 + p] += sAcc[p];
                    Lq[w][curSet][c0 + p] += qAcc[p];
                    sAcc[p] = 0.f; qAcc[p] = 0.f;
                    if (POOL) {
                        Lmx[w][curSet][c0 + p] = fmaxf(Lmx[w][curSet][c0 + p], mxA[p]);
                        Lmn[w][curSet][c0 + p] = fminf(Lmn[w][curSet][c0 + p], mnA[p]);
                        mxA[p] = -3e38f; mnA[p] = 3e38f;
                    }
                }
                curSet = bset;
            }
            float rh = 1.f / den;
            unsigned int o4[4];
#pragma unroll
            for (int p = 0; p < 4; ++p) {
                float v0 = fmaf(num[2 * p], rh, bv[2 * p]);
                float v1 = fmaf(num[2 * p + 1], rh, bv[2 * p + 1]);
                v0 = v0 > 0.f ? v0 : __expf(v0) - 1.f;  // ELU
                v1 = v1 > 0.f ? v1 : __expf(v1) - 1.f;
                sAcc[2 * p] += v0; qAcc[2 * p] += v0 * v0;
                sAcc[2 * p + 1] += v1; qAcc[2 * p + 1] += v1 * v1;
                if (POOL) {
                    mxA[2 * p] = fmaxf(mxA[2 * p], v0);
                    mnA[2 * p] = fminf(mnA[2 * p], v0);
                    mxA[2 * p + 1] = fmaxf(mxA[2 * p + 1], v1);
                    mnA[2 * p + 1] = fminf(mnA[2 * p + 1], v1);
                }
                o4[p] = ((unsigned int)(unsigned short)f2bs(v0)) |
                        (((unsigned int)(unsigned short)f2bs(v1)) << 16);
            }
            out[n * 16 + li] = make_uint4(o4[0], o4[1], o4[2], o4[3]);
        }
    }
    // final flush
    if (slot == 0) {
#pragma unroll
        for (int p = 0; p < 8; ++p) {
            Ls[w][curSet][c0 + p] += sAcc[p];
            Lq[w][curSet][c0 + p] += qAcc[p];
            if (POOL) {
                Lmx[w][curSet][c0 + p] = fmaxf(Lmx[w][curSet][c0 + p], mxA[p]);
                Lmn[w][curSet][c0 + p] = fminf(Lmn[w][curSet][c0 + p], mnA[p]);
            }
        }
    }
    __syncthreads();
    if (countFlag && tid < 64) {
        int n = base + tid;
        if (n < N) atomicAdd(&cnt2[(batch[n] != g0) ? 1 : 0], 1);
    }
    if (tid < 128) {
        float s0 = Ls[0][0][tid] + Ls[1][0][tid] + Ls[2][0][tid] + Ls[3][0][tid];
        float q0 = Lq[0][0][tid] + Lq[1][0][tid] + Lq[2][0][tid] + Lq[3][0][tid];
        atomicAdd(&gsum[g0 * 128 + tid], s0);
        atomicAdd(&gsq[g0 * 128 + tid], q0);
        if (POOL) {
            float m0 = fmaxf(fmaxf(Lmx[0][0][tid], Lmx[1][0][tid]),
                             fmaxf(Lmx[2][0][tid], Lmx[3][0][tid]));
            float n0 = fminf(fminf(Lmn[0][0][tid], Lmn[1][0][tid]),
                             fminf(Lmn[2][0][tid], Lmn[3][0][tid]));
            if (m0 > -2e38f) atomicMax(&rawmax[g0 * 128 + tid], flipf(m0));
            if (n0 < 2e38f) atomicMin(&rawmin[g0 * 128 + tid], flipf(n0));
        }
        if (g1 != g0) {
            float s1 = Ls[0][1][tid] + Ls[1][1][tid] + Ls[2][1][tid] + Ls[3][1][tid];
            float q1 = Lq[0][1][tid] + Lq[1][1][tid] + Lq[2][1][tid] + Lq[3][1][tid];
            atomicAdd(&gsum[g1 * 128 + tid], s1);
            atomicAdd(&gsq[g1 * 128 + tid], q1);
            if (POOL) {
                float m1 = fmaxf(fmaxf(Lmx[0][1][tid], Lmx[1][1][tid]),
                                 fmaxf(Lmx[2][1][tid], Lmx[3][1][tid]));
                float n1 = fminf(fminf(Lmn[0][1][tid], Lmn[1][1][tid]),
                                 fminf(Lmn[2][1][tid], Lmn[3][1][tid]));
                if (m1 > -2e38f) atomicMax(&rawmax[g1 * 128 + tid], flipf(m1));
                if (n1 < 2e38f) atomicMin(&rawmin[g1 * 128 + tid], flipf(n1));
            }
        }
    }
    __syncthreads();
    if (countFlag && tid < 2) {
        int g = (tid == 0) ? g0 : g1;
        if ((tid == 0 || g1 != g0) && cnt2[tid]) atomicAdd(&gcnt[g], cnt2[tid]);
    }
}

// ---------------- GraphNorm coefficients ----------------
__global__ void norm_coef(const float* __restrict__ gsum, const float* __restrict__ gsq,
                          const int* __restrict__ gcnt,
                          const float* __restrict__ w, const float* __restrict__ b,
                          const float* __restrict__ ms,
                          float* __restrict__ Ac, float* __restrict__ Bc) {
    int g = blockIdx.x, c = threadIdx.x;
    int i = g * 128 + c;
    float cntv = (float)gcnt[g];
    if (cntv < 0.5f) { Ac[i] = 0.f; Bc[i] = 0.f; return; }
    float mean = gsum[i] / cntv;
    float msv = ms[c];
    float var = gsq[i] / cntv - msv * (2.f - msv) * mean * mean;
    var = fmaxf(var, 0.f);
    float inv = rsqrtf(var + EPS_GN);
    float wv = w[c];
    Ac[i] = wv * inv;
    Bc[i] = b[c] - msv * mean * wv * inv;
}

// -------- FC with fused normalize-of-pooled-extrema --------------------------
// GraphNorm is affine per (g,c): monotone, so segment_max(norm(x)) =
// Ac>=0 ? Ac*max(x)+Bc : Ac*min(x)+Bc.
__global__ void fc_kernel(const unsigned int* __restrict__ rawmax,
                          const unsigned int* __restrict__ rawmin,
                          const float* __restrict__ Ac, const float* __restrict__ Bc,
                          const float* __restrict__ fcw,
                          const float* __restrict__ fcb,
                          float* __restrict__ out) {
    int g = blockIdx.x, o = threadIdx.x;  // 64 x 64
    __shared__ float p[128];
#pragma unroll
    for (int h = 0; h < 2; ++h) {
        int c = o + h * 64;
        float a = Ac[g * 128 + c], bb = Bc[g * 128 + c];
        float M = unflipf(rawmax[g * 128 + c]);
        float m = unflipf(rawmin[g * 128 + c]);
        p[c] = (a >= 0.f) ? fmaf(a, M, bb) : fmaf(a, m, bb);
    }
    __syncthreads();
    float acc = fcb[o];
    for (int k = 0; k < 128; ++k)
        acc = fmaf(p[k], fcw[o * 128 + k], acc);
    out[g * 64 + o] = acc;
}

extern "C" void kernel_launch(void* const* d_in, const int* in_sizes, int n_in,
                              void* d_out, int out_size, void* d_ws, size_t ws_size,
                              hipStream_t stream) {
    const float* x     = (const float*)d_in[0];
    const int* ei      = (const int*)d_in[1];
    const int* batch   = (const int*)d_in[2];
    const float* enc_w = (const float*)d_in[3];
    const float* enc_b = (const float*)d_in[4];
    const float* w1    = (const float*)d_in[5];
    const float* as1   = (const float*)d_in[6];
    const float* ad1   = (const float*)d_in[7];
    const float* b1    = (const float*)d_in[8];
    const float* n1w   = (const float*)d_in[9];
    const float* n1b   = (const float*)d_in[10];
    const float* n1ms  = (const float*)d_in[11];
    const float* w2    = (const float*)d_in[12];
    const float* as2   = (const float*)d_in[13];
    const float* ad2   = (const float*)d_in[14];
    const float* b2    = (const float*)d_in[15];
    const float* n2w   = (const float*)d_in[16];
    const float* n2b   = (const float*)d_in[17];
    const float* n2ms  = (const float*)d_in[18];
    const float* fcw   = (const float*)d_in[19];
    const float* fcb   = (const float*)d_in[20];
    float* out = (float*)d_out;

    int N = in_sizes[2];
    int E = in_sizes[1] / 2;
    int Etot = E + N;

    char* ws = (char*)d_ws;
    size_t off = 0;
    auto take = [&](size_t bytes) {
        char* p = ws + off;
        off = (off + bytes + 255) & ~(size_t)255;
        return p;
    };
    unsigned short* WT1b = (unsigned short*)take(128 * 128 * 2);
    unsigned short* WT2b = (unsigned short*)take(128 * 128 * 2);
    float* bc1 = (float*)take(512);
    float* bc2 = (float*)take(512);
    float* ssrc = (float*)take((size_t)N * 16);
    float* sdst = (float*)take((size_t)N * 16);
    int* rowp   = (int*)take((size_t)(N + 1) * 4);
    int* esrc   = (int*)take((size_t)Etot * 4);
    unsigned int* staging = (unsigned int*)take((size_t)Etot * 4);
    int* bbase  = (int*)take(512 * 4);
    int* bcur   = (int*)take(512 * 4);
    unsigned int* H = (unsigned int*)take((size_t)N * 256);  // bf16 [N][128]
    unsigned int* AG = (unsigned int*)take((size_t)N * 256); // bf16 [N][128]
    float* Ac   = (float*)take(64 * 128 * 4);
    float* Bc   = (float*)take(64 * 128 * 4);
    unsigned int* rawmin = (unsigned int*)take(64 * 128 * 4);  // memset 0xFF
    // --- contiguous zero span (one zero_kernel covers all of these) ---
    size_t zbeg = off;
    int* bhist   = (int*)take(512 * 4);
    float* gsumA = (float*)take(64 * 128 * 4);
    float* gsqA  = (float*)take(64 * 128 * 4);
    float* gsumB = (float*)take(64 * 128 * 4);
    float* gsqB  = (float*)take(64 * 128 * 4);
    int* gcnt    = (int*)take(256);
    unsigned int* rawmax = (unsigned int*)take(64 * 128 * 4);  // flip(any) > 0
    size_t zend = off;
    if (off > ws_size) return;  // workspace too small -> output stays zero

    int zn = (int)((zend - zbeg) / 4);
    int EB = (Etot + 4095) / 4096;

    zero_kernel<<<(zn + 255) / 256, 256, 0, stream>>>((float*)(ws + zbeg), zn);
    hipMemsetAsync(rawmin, 0xFF, 64 * 128 * 4, stream);
    prep_weights<<<128, 128, 0, stream>>>(enc_w, enc_b, w1, w2, WT1b, WT2b, bc1, bc2);

    // ---- CSR build (bucketed counting sort) ----
    bucket_hist<<<EB, 256, 0, stream>>>(ei, bhist, E, N);
    bucket_scan<<<1, 512, 0, stream>>>(bhist, bbase, bcur);
    bucket_scatter<<<EB, 256, 0, stream>>>(ei, bcur, staging, E, N);
    bucket_finalize<<<NBUCK, 256, 0, stream>>>(staging, bbase, bcur, rowp, esrc, N, Etot);

    // ---- layer 1 (encoder folded into WT1b/bc1; stats fused into agg) ----
    gemm_mfma<<<(N + 63) / 64, 256, 0, stream>>>(x, WT1b, bc1, as1, ad1, batch,
                                                 nullptr, nullptr, H, ssrc, sdst, N);
    agg_kernel<0><<<(N + 63) / 64, 256, 0, stream>>>(
        rowp, esrc, ssrc, sdst, (const uint4*)H, b1, (uint4*)AG, batch,
        gsumA, gsqA, gcnt, 1, nullptr, nullptr, N);
    norm_coef<<<64, 128, 0, stream>>>(gsumA, gsqA, gcnt, n1w, n1b, n1ms, Ac, Bc);

    // ---- layer 2 (GraphNorm fused into gemm A-staging; stats+pool in agg) ----
    gemm_mfma<<<(N + 63) / 64, 256, 0, stream>>>(AG, WT2b, bc2, as2, ad2, batch,
                                                 Ac, Bc, H, ssrc, sdst, N);
    agg_kernel<1><<<(N + 63) / 64, 256, 0, stream>>>(
        rowp, esrc, ssrc, sdst, (const uint4*)H, b2, (uint4*)AG, batch,
        gsumB, gsqB, gcnt, 0, rawmax, rawmin, N);
    norm_coef<<<64, 128, 0, stream>>>(gsumB, gsqB, gcnt, n2w, n2b, n2ms, Ac, Bc);

    fc_kernel<<<64, 64, 0, stream>>>(rawmax, rawmin, Ac, Bc, fcw, fcb, out);
}